// Round 1
// baseline (39.901 us; speedup 1.0000x reference)
//
#include <hip/hip_runtime.h>
#include <math.h>

#define N 4096
#define MARGINF 2.0f
#define EPSF 1e-4f

constexpr int NROWBLK = N / 256;   // 16 row blocks of 256 rows
constexpr int NCH = 8;             // column chunks
constexpr int CHUNK = N / NCH;     // 512 columns per chunk
constexpr int GRAD_OFF = 16;       // float offset of grad partials in ws

// ws layout (floats):
//   [0..4]                      full-matrix ranking sums (streams 0..3 = scores, 4 = pred)
//   [GRAD_OFF + ch*N + row]     grad partial for pred stream, per column-chunk

__global__ __launch_bounds__(256) void pair_kernel(
    const float* __restrict__ scores, const float* __restrict__ pred,
    const float* __restrict__ label, float* __restrict__ ws)
{
    __shared__ float lds[4];
    const int bid = blockIdx.x;
    const int stream = bid / (NROWBLK * NCH);
    const int rem = bid % (NROWBLK * NCH);
    const int rowblk = rem / NCH;
    const int ch = rem % NCH;
    const bool isPred = (stream == 4);
    const float* __restrict__ p = isPred ? pred : (scores + stream * N);

    const int row = rowblk * 256 + threadIdx.x;
    const float rk = p[row];
    const float lk = label[row];
    const int c0 = ch * CHUNK;

    float sum = 0.f;

    if (!isPred) {
        #pragma unroll 8
        for (int c = c0; c < c0 + CHUNK; ++c) {
            const float lm = label[c];
            const float pm = p[c];
            const float ld = lm - lk;
            const float pd = pm - rk;
            const unsigned sgn = __float_as_uint(ld) & 0x80000000u;
            const float x = __uint_as_float(__float_as_uint(pd) ^ sgn); // pd * sign(ld)
            const float z = MARGINF - x;
            sum += fmaxf(z, 0.f);
        }
    } else {
        float grad = 0.f;
        #pragma unroll 8
        for (int c = c0; c < c0 + CHUNK; ++c) {
            const float lm = label[c];
            const float pm = p[c];
            const float ld = lm - lk;
            const float pd = pm - rk;
            const unsigned sgn = __float_as_uint(ld) & 0x80000000u;
            const float x = __uint_as_float(__float_as_uint(pd) ^ sgn);
            const float z = MARGINF - x;
            sum += fmaxf(z, 0.f);
            const float sf = __uint_as_float(0x3f800000u ^ sgn);       // +-1.0f
            grad += (z > 0.f) ? sf : 0.f;
        }
        // remove spurious diagonal contribution (ld=0 -> sgn=+ -> +1, ref has sign(0)=0)
        if (row >= c0 && row < c0 + CHUNK) grad -= 1.0f;
        ws[GRAD_OFF + ch * N + row] = grad;
    }

    // block reduce sum -> one atomic per block
    #pragma unroll
    for (int off = 32; off > 0; off >>= 1)
        sum += __shfl_xor(sum, off, 64);
    const int wid = threadIdx.x >> 6;
    const int lane = threadIdx.x & 63;
    if (lane == 0) lds[wid] = sum;
    __syncthreads();
    if (threadIdx.x == 0) {
        const float total = lds[0] + lds[1] + lds[2] + lds[3];
        atomicAdd(&ws[stream], total);
    }
}

__global__ __launch_bounds__(256) void finalize_kernel(
    const float* __restrict__ pred, const float* __restrict__ label,
    const float* __restrict__ ws, float* __restrict__ out)
{
    __shared__ float lds[8];
    const int tid = threadIdx.x;
    float sse = 0.f, g2sq = 0.f;
    for (int i = tid; i < N; i += 256) {
        const float d = pred[i] - label[i];
        sse += d * d;
        float g = 0.f;
        #pragma unroll
        for (int ch = 0; ch < NCH; ++ch) g += ws[GRAD_OFF + ch * N + i];
        g2sq += g * g;
    }
    #pragma unroll
    for (int off = 32; off > 0; off >>= 1) {
        sse  += __shfl_xor(sse,  off, 64);
        g2sq += __shfl_xor(g2sq, off, 64);
    }
    const int wid = tid >> 6;
    const int lane = tid & 63;
    if (lane == 0) { lds[wid] = sse; lds[4 + wid] = g2sq; }
    __syncthreads();
    if (tid == 0) {
        const float sseT  = lds[0] + lds[1] + lds[2] + lds[3];
        const float g2sqT = lds[4] + lds[5] + lds[6] + lds[7];
        float branch = 0.f;
        #pragma unroll
        for (int s = 0; s < 4; ++s)
            branch += (ws[s] - (float)N * MARGINF) * 0.5f;
        const float rankp = (ws[4] - (float)N * MARGINF) * 0.5f;
        const float mse = sseT / (float)N;
        const float g1 = (2.0f / (float)N) * sqrtf(sseT);
        const float g2 = sqrtf(g2sqT);
        const float beta = g1 / (g2 + EPSF);
        out[0] = 0.25f * branch + mse + beta * rankp;
    }
}

extern "C" void kernel_launch(void* const* d_in, const int* in_sizes, int n_in,
                              void* d_out, int out_size, void* d_ws, size_t ws_size,
                              hipStream_t stream) {
    const float* scores = (const float*)d_in[0];
    const float* pred   = (const float*)d_in[1];
    const float* label  = (const float*)d_in[2];
    float* ws  = (float*)d_ws;
    float* out = (float*)d_out;

    // zero the 5 ranking accumulators (atomics target) every call
    hipMemsetAsync(d_ws, 0, 64, stream);

    const int nblocks = 5 * NROWBLK * NCH; // 640
    pair_kernel<<<nblocks, 256, 0, stream>>>(scores, pred, label, ws);
    finalize_kernel<<<1, 256, 0, stream>>>(pred, label, ws, out);
}

// Round 2
// 35.460 us; speedup vs baseline: 1.1252x; 1.1252x over previous
//
#include <hip/hip_runtime.h>
#include <math.h>

#define N 4096
#define MARGINF 2.0f
#define EPSF 1e-4f

constexpr int NROWBLK = N / 256;       // 16 row blocks of 256 rows
constexpr int NCH = 8;                 // column chunks
constexpr int CHUNK = N / NCH;         // 512 columns per chunk
constexpr int NBLK = 5 * NROWBLK * NCH;       // 640 blocks
constexpr int BLK_PER_STREAM = NROWBLK * NCH; // 128
constexpr int GRAD_OFF = 1024;         // float offset of grad partials in ws

// ws layout (floats) — all slots pure-written every call (no zero-init needed):
//   [0..639]                    per-block rank partials (blocks 0..511 = scores, 512..639 = pred)
//   [GRAD_OFF + ch*N + row]     grad partial for pred stream, per column-chunk

__global__ __launch_bounds__(256) void pair_kernel(
    const float* __restrict__ scores, const float* __restrict__ pred,
    const float* __restrict__ label, float* __restrict__ ws)
{
    __shared__ float lds[4];
    const int bid = blockIdx.x;
    const int stream = bid / BLK_PER_STREAM;
    const int rem = bid % BLK_PER_STREAM;
    const int rowblk = rem / NCH;
    const int ch = rem % NCH;
    const bool isPred = (stream == 4);
    const float* __restrict__ p = isPred ? pred : (scores + stream * N);

    const int row = rowblk * 256 + threadIdx.x;
    const float rk = p[row];
    const float lk = label[row];
    const int c0 = ch * CHUNK;

    float sum = 0.f;

    if (!isPred) {
        #pragma unroll 8
        for (int c = c0; c < c0 + CHUNK; ++c) {
            const float lm = label[c];
            const float pm = p[c];
            const float ld = lm - lk;
            const float pd = pm - rk;
            const unsigned sgn = __float_as_uint(ld) & 0x80000000u;
            const float x = __uint_as_float(__float_as_uint(pd) ^ sgn); // pd * sign(ld)
            sum += fmaxf(MARGINF - x, 0.f);
        }
    } else {
        float grad = 0.f;
        #pragma unroll 8
        for (int c = c0; c < c0 + CHUNK; ++c) {
            const float lm = label[c];
            const float pm = p[c];
            const float ld = lm - lk;
            const float pd = pm - rk;
            const unsigned sgn = __float_as_uint(ld) & 0x80000000u;
            const float x = __uint_as_float(__float_as_uint(pd) ^ sgn);
            const float z = MARGINF - x;
            sum += fmaxf(z, 0.f);
            const float sf = __uint_as_float(0x3f800000u ^ sgn);       // +-1.0f
            grad += (z > 0.f) ? sf : 0.f;
        }
        // remove spurious diagonal contribution (ld=0 -> sgn=+ -> +1, ref has sign(0)=0)
        if (row >= c0 && row < c0 + CHUNK) grad -= 1.0f;
        ws[GRAD_OFF + ch * N + row] = grad;
    }

    // block reduce -> one pure store per block (no atomics, no zeroed memory)
    #pragma unroll
    for (int off = 32; off > 0; off >>= 1)
        sum += __shfl_xor(sum, off, 64);
    const int wid = threadIdx.x >> 6;
    const int lane = threadIdx.x & 63;
    if (lane == 0) lds[wid] = sum;
    __syncthreads();
    if (threadIdx.x == 0)
        ws[bid] = lds[0] + lds[1] + lds[2] + lds[3];
}

__global__ __launch_bounds__(256) void finalize_kernel(
    const float* __restrict__ pred, const float* __restrict__ label,
    const float* __restrict__ ws, float* __restrict__ out)
{
    __shared__ float lds[16];
    const int tid = threadIdx.x;

    float sse = 0.f, g2sq = 0.f;
    for (int i = tid; i < N; i += 256) {
        const float d = pred[i] - label[i];
        sse += d * d;
        float g = 0.f;
        #pragma unroll
        for (int ch = 0; ch < NCH; ++ch) g += ws[GRAD_OFF + ch * N + i];
        g2sq += g * g;
    }

    // rank partial sums: branch = ws[0..511], predrank = ws[512..639]
    float br = ws[tid] + ws[tid + 256];
    float pr = (tid < 128) ? ws[512 + tid] : 0.f;

    #pragma unroll
    for (int off = 32; off > 0; off >>= 1) {
        sse  += __shfl_xor(sse,  off, 64);
        g2sq += __shfl_xor(g2sq, off, 64);
        br   += __shfl_xor(br,   off, 64);
        pr   += __shfl_xor(pr,   off, 64);
    }
    const int wid = tid >> 6;
    const int lane = tid & 63;
    if (lane == 0) {
        lds[wid] = sse; lds[4 + wid] = g2sq;
        lds[8 + wid] = br; lds[12 + wid] = pr;
    }
    __syncthreads();
    if (tid == 0) {
        const float sseT  = lds[0] + lds[1] + lds[2] + lds[3];
        const float g2sqT = lds[4] + lds[5] + lds[6] + lds[7];
        const float brT   = lds[8] + lds[9] + lds[10] + lds[11];
        const float prT   = lds[12] + lds[13] + lds[14] + lds[15];
        // per-stream full-matrix sum -> upper-tri: (full - n*margin)/2, 4 streams
        const float branch = (brT - 4.0f * (float)N * MARGINF) * 0.5f;
        const float rankp  = (prT - (float)N * MARGINF) * 0.5f;
        const float mse = sseT / (float)N;
        const float g1 = (2.0f / (float)N) * sqrtf(sseT);
        const float g2 = sqrtf(g2sqT);
        const float beta = g1 / (g2 + EPSF);
        out[0] = 0.25f * branch + mse + beta * rankp;
    }
}

extern "C" void kernel_launch(void* const* d_in, const int* in_sizes, int n_in,
                              void* d_out, int out_size, void* d_ws, size_t ws_size,
                              hipStream_t stream) {
    const float* scores = (const float*)d_in[0];
    const float* pred   = (const float*)d_in[1];
    const float* label  = (const float*)d_in[2];
    float* ws  = (float*)d_ws;
    float* out = (float*)d_out;

    pair_kernel<<<NBLK, 256, 0, stream>>>(scores, pred, label, ws);
    finalize_kernel<<<1, 256, 0, stream>>>(pred, label, ws, out);
}

// Round 3
// 23.911 us; speedup vs baseline: 1.6687x; 1.4830x over previous
//
#include <hip/hip_runtime.h>
#include <math.h>

#define N 4096
#define MARGINF 2.0f
#define EPSF 1e-4f

constexpr int TILE = 256;                     // tile rows & cols
constexpr int NT = N / TILE;                  // 16
constexpr int NDIAGTILES = NT * (NT + 1) / 2; // 136 upper-tri tiles per stream
constexpr int NSCORE_BLK = 4 * NDIAGTILES;    // 544
constexpr int NPRED_BLK = NT * NT;            // 256
constexpr int NBLK = NSCORE_BLK + NPRED_BLK;  // 800
constexpr int GRAD_OFF = 1024;                // float offset of grad partials

// ws layout (floats), all pure-written every call:
//   [0..543]            score triangle partials (sum over i<j directly)
//   [544..799]          pred full-matrix partials
//   [GRAD_OFF + r*16+c] grad partial for pred row r, column-chunk c (c in [0,16))

__global__ __launch_bounds__(256) void pair_kernel(
    const float* __restrict__ scores, const float* __restrict__ pred,
    const float* __restrict__ label, float* __restrict__ ws)
{
    __shared__ __align__(16) float lds_l[TILE];
    __shared__ __align__(16) float lds_p[TILE];
    __shared__ float red[4];

    const int bid = blockIdx.x;
    const int tid = threadIdx.x;
    float sum = 0.f;

    if (bid < NSCORE_BLK) {
        // ---- score streams: strict upper-triangle tiles, sum only ----
        const int stream = bid / NDIAGTILES;
        int t = bid % NDIAGTILES;
        int ti = 0;
        while (t >= NT - ti) { t -= NT - ti; ++ti; }  // scalar, <=16 iters
        const int tj = ti + t;                        // tj >= ti
        const float* __restrict__ p = scores + stream * N;

        const int r = ti * TILE + tid;
        const int c0 = tj * TILE;
        lds_l[tid] = label[c0 + tid];
        lds_p[tid] = p[c0 + tid];
        __syncthreads();
        const float rk = p[r];
        const float lk = label[r];

        if (ti != tj) {
            // full tile: every col > every row
            #pragma unroll 2
            for (int j = 0; j < TILE; j += 4) {
                const float4 l4 = *(const float4*)&lds_l[j];
                const float4 p4 = *(const float4*)&lds_p[j];
                auto body = [&](float lm, float pm) {
                    const unsigned sgn = __float_as_uint(lm - lk) & 0x80000000u;
                    const float x = __uint_as_float(__float_as_uint(pm - rk) ^ sgn);
                    sum += fmaxf(MARGINF - x, 0.f);
                };
                body(l4.x, p4.x); body(l4.y, p4.y);
                body(l4.z, p4.z); body(l4.w, p4.w);
            }
        } else {
            // diagonal tile: only cols with (j+u) > tid count
            #pragma unroll 2
            for (int j = 0; j < TILE; j += 4) {
                const float4 l4 = *(const float4*)&lds_l[j];
                const float4 p4 = *(const float4*)&lds_p[j];
                auto body = [&](float lm, float pm, int cc) {
                    const unsigned sgn = __float_as_uint(lm - lk) & 0x80000000u;
                    const float x = __uint_as_float(__float_as_uint(pm - rk) ^ sgn);
                    const float h = fmaxf(MARGINF - x, 0.f);
                    sum += (cc > tid) ? h : 0.f;
                };
                body(l4.x, p4.x, j + 0); body(l4.y, p4.y, j + 1);
                body(l4.z, p4.z, j + 2); body(l4.w, p4.w, j + 3);
            }
        }
    } else {
        // ---- pred stream: full matrix (grad needed), 256x256 tiles ----
        const int rem = bid - NSCORE_BLK;
        const int rowblk = rem >> 4;
        const int ch = rem & (NT - 1);
        const int r = rowblk * TILE + tid;
        const int c0 = ch * TILE;
        lds_l[tid] = label[c0 + tid];
        lds_p[tid] = pred[c0 + tid];
        __syncthreads();
        const float rk = pred[r];
        const float lk = label[r];

        float grad = 0.f;
        #pragma unroll 2
        for (int j = 0; j < TILE; j += 4) {
            const float4 l4 = *(const float4*)&lds_l[j];
            const float4 p4 = *(const float4*)&lds_p[j];
            auto body = [&](float lm, float pm) {
                const unsigned sgn = __float_as_uint(lm - lk) & 0x80000000u;
                const float x = __uint_as_float(__float_as_uint(pm - rk) ^ sgn);
                const float z = MARGINF - x;
                sum += fmaxf(z, 0.f);
                const float sf = __uint_as_float(0x3f800000u ^ sgn); // +-1.0f
                grad += (z > 0.f) ? sf : 0.f;
            };
            body(l4.x, p4.x); body(l4.y, p4.y);
            body(l4.z, p4.z); body(l4.w, p4.w);
        }
        // remove spurious diagonal contribution (sign(0)=0 in ref)
        if (rowblk == ch) grad -= 1.0f;
        ws[GRAD_OFF + r * 16 + ch] = grad;
    }

    // block reduce -> one pure store per block
    #pragma unroll
    for (int off = 32; off > 0; off >>= 1)
        sum += __shfl_xor(sum, off, 64);
    const int wid = tid >> 6;
    const int lane = tid & 63;
    if (lane == 0) red[wid] = sum;
    __syncthreads();
    if (tid == 0)
        ws[bid] = red[0] + red[1] + red[2] + red[3];
}

__global__ __launch_bounds__(256) void finalize_kernel(
    const float* __restrict__ pred, const float* __restrict__ label,
    const float* __restrict__ ws, float* __restrict__ out)
{
    __shared__ float lds[16];
    const int tid = threadIdx.x;

    float sse = 0.f, g2sq = 0.f;
    #pragma unroll
    for (int k = 0; k < NT; ++k) {
        const int i = k * 256 + tid;
        const float d = pred[i] - label[i];
        sse += d * d;
        const float4* gp = (const float4*)(ws + GRAD_OFF + i * 16);
        const float4 a = gp[0], b = gp[1], c = gp[2], e = gp[3];
        const float g = (a.x + a.y + a.z + a.w) + (b.x + b.y + b.z + b.w)
                      + (c.x + c.y + c.z + c.w) + (e.x + e.y + e.z + e.w);
        g2sq += g * g;
    }

    float br = ws[tid] + ws[tid + 256] + ((tid < 32) ? ws[512 + tid] : 0.f);
    float pr = ws[NSCORE_BLK + tid];

    #pragma unroll
    for (int off = 32; off > 0; off >>= 1) {
        sse  += __shfl_xor(sse,  off, 64);
        g2sq += __shfl_xor(g2sq, off, 64);
        br   += __shfl_xor(br,   off, 64);
        pr   += __shfl_xor(pr,   off, 64);
    }
    const int wid = tid >> 6;
    const int lane = tid & 63;
    if (lane == 0) {
        lds[wid] = sse; lds[4 + wid] = g2sq;
        lds[8 + wid] = br; lds[12 + wid] = pr;
    }
    __syncthreads();
    if (tid == 0) {
        const float sseT  = lds[0] + lds[1] + lds[2] + lds[3];
        const float g2sqT = lds[4] + lds[5] + lds[6] + lds[7];
        const float brT   = lds[8] + lds[9] + lds[10] + lds[11];   // already i<j only
        const float prT   = lds[12] + lds[13] + lds[14] + lds[15]; // full matrix
        const float rankp = (prT - (float)N * MARGINF) * 0.5f;
        const float mse = sseT / (float)N;
        const float g1 = (2.0f / (float)N) * sqrtf(sseT);
        const float g2 = sqrtf(g2sqT);
        const float beta = g1 / (g2 + EPSF);
        out[0] = 0.25f * brT + mse + beta * rankp;
    }
}

extern "C" void kernel_launch(void* const* d_in, const int* in_sizes, int n_in,
                              void* d_out, int out_size, void* d_ws, size_t ws_size,
                              hipStream_t stream) {
    const float* scores = (const float*)d_in[0];
    const float* pred   = (const float*)d_in[1];
    const float* label  = (const float*)d_in[2];
    float* ws  = (float*)d_ws;
    float* out = (float*)d_out;

    pair_kernel<<<NBLK, 256, 0, stream>>>(scores, pred, label, ws);
    finalize_kernel<<<1, 256, 0, stream>>>(pred, label, ws, out);
}